// Round 8
// baseline (131.299 us; speedup 1.0000x reference)
//
#include <hip/hip_runtime.h>
#include <stdint.h>

// Problem constants
#define BB      131072
#define TT      100
#define DT_C    0.01f
#define GAMMA_C 0.05f
#define I0_C    0.12f

typedef short bf16x8 __attribute__((ext_vector_type(8)));
typedef float f32x4  __attribute__((ext_vector_type(4)));

// ws layout: 38 B-fragments (bf16 as u16). Bias folded in as extra K-row
// (k=100 for L0, k=50 for L1/L2, paired with activation 1.0). W2,b2 pre-scaled by dt.
// Fragment = 1024 B; lane L holds B[k=kc*32+(L>>4)*8+j][n=nt*16+(L&15)], j=0..7.
#define F0_U16  0           // L0: 16 frags (kc 0..3, nt 0..3), K=100+bias->128, N=50->64
#define F1_U16  (16*512)    // L1: 8 frags  (kc 0..1, nt 0..3), K=50+bias->64,  N=50->64
#define F2_U16  (24*512)    // L2: 14 frags (kc 0..1, nt 0..6), K=50+bias->64,  N=99->112
#define NFRAG_U16 (38*512)  // 19456 u16 = 38,912 B

__device__ __forceinline__ uint16_t f2bf(float x) {
    uint32_t u = __builtin_bit_cast(uint32_t, x);
    return (uint16_t)((u + 0x7fffu + ((u >> 16) & 1u)) >> 16);   // RTNE
}
__device__ __forceinline__ uint32_t pk2(float a, float b) {
    return (uint32_t)f2bf(a) | ((uint32_t)f2bf(b) << 16);
}

__global__ void pack_kernel(const float* __restrict__ W0, const float* __restrict__ b0,
                            const float* __restrict__ W1, const float* __restrict__ b1,
                            const float* __restrict__ W2, const float* __restrict__ b2,
                            uint16_t* __restrict__ wsu)
{
    const int gid = blockIdx.x * blockDim.x + threadIdx.x;
    const int gsz = gridDim.x * blockDim.x;
    for (int idx = gid; idx < NFRAG_U16; idx += gsz) {
        int f = idx >> 9;
        int r = idx & 511;
        int L = r >> 3, j = r & 7;
        int k8 = ((L >> 4) << 3) + j;
        int n16 = L & 15;
        float v = 0.0f;
        if (f < 16) {                    // B0[k][n]: W0[n][k] for k<100; b0[n] at k==100
            int kc = f >> 2, nt = f & 3;
            int kk = kc * 32 + k8, nn = nt * 16 + n16;
            if (nn < 50) {
                if (kk < 100) v = W0[nn * 100 + kk];
                else if (kk == 100) v = b0[nn];
            }
        } else if (f < 24) {             // B1[k][n]: W1[n][k] for k<50; b1[n] at k==50
            int g = f - 16; int kc = g >> 2, nt = g & 3;
            int kk = kc * 32 + k8, nn = nt * 16 + n16;
            if (nn < 50) {
                if (kk < 50) v = W1[nn * 50 + kk];
                else if (kk == 50) v = b1[nn];
            }
        } else {                         // B2[k][t]: dt*W2[t][k] for k<50; dt*b2[t] at k==50
            int g = f - 24; int kc = g / 7, nt = g % 7;
            int kk = kc * 32 + k8, nn = nt * 16 + n16;
            if (nn < 99) {
                if (kk < 50) v = DT_C * W2[nn * 50 + kk];
                else if (kk == 50) v = DT_C * b2[nn];
            }
        }
        wsu[idx] = f2bf(v);
    }
}

// Per-wave LDS slab (wave-private -> NO barriers anywhere):
//   h0: u16 [16 m][88 n]  at +0 B      (2816 B)
//   h1: u16 [16 m][88 n]  at +2816 B   (2816 B)
//   O:  f32 [16 m][116 t] at +0 B      (7424 B), overlays h0/h1 after a2 regs are loaded
// Row stride 116 f32 = 464 B = 29*16 -> every row 16B-aligned for ds_read_b128.
#define SLAB_F 1856   // 16*116 floats per wave

__global__ __launch_bounds__(256, 4) void net_kernel(
    const float* __restrict__ x,
    const void*  __restrict__ wsv,
    float* __restrict__ out)
{
    __shared__ float lds[4 * SLAB_F];    // 29,696 B -> 4 blocks/CU (16 waves/CU)
    const int tid  = threadIdx.x;
    const int wave = tid >> 6, lane = tid & 63;
    const int quad = lane >> 4, l15 = lane & 15;
    float* slabF = lds + wave * SLAB_F;
    uint16_t* h0u = (uint16_t*)slabF;
    uint16_t* h1u = (uint16_t*)slabF + 16 * 88;
    const uint16_t* wsu = (const uint16_t*)wsv;

    const int row0 = (blockIdx.x * 4 + wave) * 16;   // this wave's 16 batch rows

    // ================= A0 fragments: f32 -> bf16 =================
    bf16x8 a0[4];
    {
        const float* xrow = x + (size_t)(row0 + l15) * 100;
        #pragma unroll
        for (int kc = 0; kc < 3; ++kc) {
            f32x4 p = *(const f32x4*)(xrow + kc * 32 + quad * 8);
            f32x4 q = *(const f32x4*)(xrow + kc * 32 + quad * 8 + 4);
            union { bf16x8 v; uint32_t u[4]; } t;
            t.u[0] = pk2(p[0], p[1]); t.u[1] = pk2(p[2], p[3]);
            t.u[2] = pk2(q[0], q[1]); t.u[3] = pk2(q[2], q[3]);
            a0[kc] = t.v;
        }
        union { bf16x8 v; uint32_t u[4]; } t;
        t.u[0] = t.u[1] = t.u[2] = t.u[3] = 0u;
        if (quad == 0) {                       // k 96..99 from x; k=100 = bias activation 1.0
            f32x4 p = *(const f32x4*)(xrow + 96);
            t.u[0] = pk2(p[0], p[1]); t.u[1] = pk2(p[2], p[3]);
            t.u[2] = 0x00003f80u;              // bf16(1.0) at k=100
        }
        a0[3] = t.v;
    }

    // ================= Layer 0: C0[16,64] = x~[16,128] * B0[128,64] =================
    f32x4 acc0[4];
    #pragma unroll
    for (int nt = 0; nt < 4; ++nt) acc0[nt] = (f32x4){0.f, 0.f, 0.f, 0.f};
    #pragma unroll
    for (int kc = 0; kc < 4; ++kc) {
        #pragma unroll
        for (int nt = 0; nt < 4; ++nt) {
            bf16x8 b = ((const bf16x8*)(wsu + F0_U16 + (kc * 4 + nt) * 512))[lane];
            acc0[nt] = __builtin_amdgcn_mfma_f32_16x16x32_bf16(a0[kc], b, acc0[nt], 0, 0, 0);
        }
    }
    // epilogue: h0 = relu(C0) bf16; n==50 gets activation 1.0 (bias row for L1)
    const bool is50 = (l15 == 2);
    #pragma unroll
    for (int nt = 0; nt < 4; ++nt) {
        const int n = nt * 16 + l15;
        #pragma unroll
        for (int r2 = 0; r2 < 4; r2 += 2) {
            float v0 = fmaxf(acc0[nt][r2], 0.0f);
            float v1 = fmaxf(acc0[nt][r2 + 1], 0.0f);
            if (nt == 3 && is50) { v0 = 1.0f; v1 = 1.0f; }
            uint32_t p = pk2(v0, v1);
            const int m = quad * 4 + r2;
            h0u[m * 88 + n]       = (uint16_t)p;
            h0u[(m + 1) * 88 + n] = (uint16_t)(p >> 16);
        }
    }

    // ================= Layer 1: C1[16,64] = h0[16,64] * B1[64,64] =================
    bf16x8 a1[2];
    #pragma unroll
    for (int kc = 0; kc < 2; ++kc)
        a1[kc] = *(const bf16x8*)(h0u + l15 * 88 + kc * 32 + quad * 8);

    f32x4 acc1[4];
    #pragma unroll
    for (int nt = 0; nt < 4; ++nt) acc1[nt] = (f32x4){0.f, 0.f, 0.f, 0.f};
    #pragma unroll
    for (int kc = 0; kc < 2; ++kc) {
        #pragma unroll
        for (int nt = 0; nt < 4; ++nt) {
            bf16x8 b = ((const bf16x8*)(wsu + F1_U16 + (kc * 4 + nt) * 512))[lane];
            acc1[nt] = __builtin_amdgcn_mfma_f32_16x16x32_bf16(a1[kc], b, acc1[nt], 0, 0, 0);
        }
    }
    #pragma unroll
    for (int nt = 0; nt < 4; ++nt) {
        const int n = nt * 16 + l15;
        #pragma unroll
        for (int r2 = 0; r2 < 4; r2 += 2) {
            float v0 = fmaxf(acc1[nt][r2], 0.0f);
            float v1 = fmaxf(acc1[nt][r2 + 1], 0.0f);
            if (nt == 3 && is50) { v0 = 1.0f; v1 = 1.0f; }
            uint32_t p = pk2(v0, v1);
            const int m = quad * 4 + r2;
            h1u[m * 88 + n]       = (uint16_t)p;
            h1u[(m + 1) * 88 + n] = (uint16_t)(p >> 16);
        }
    }

    // ================= Layer 2: O[16,112] = h1[16,64] * B2[64,112] (dt,bias folded) =================
    bf16x8 a2[2];
    #pragma unroll
    for (int kc = 0; kc < 2; ++kc)
        a2[kc] = *(const bf16x8*)(h1u + l15 * 88 + kc * 32 + quad * 8);

    f32x4 acc2[7];
    #pragma unroll
    for (int nt = 0; nt < 7; ++nt) acc2[nt] = (f32x4){0.f, 0.f, 0.f, 0.f};
    #pragma unroll
    for (int kc = 0; kc < 2; ++kc) {
        #pragma unroll
        for (int nt = 0; nt < 7; ++nt) {
            bf16x8 b = ((const bf16x8*)(wsu + F2_U16 + (kc * 7 + nt) * 512))[lane];
            acc2[nt] = __builtin_amdgcn_mfma_f32_16x16x32_bf16(a2[kc], b, acc2[nt], 0, 0, 0);
        }
    }
    // O epilogue: o' = dt*(h1.W2 + b2); cols t>=99 are zeros (zero-padded W2/b2)
    // Bank pattern per (nt,r): quad pairs alias 2-way -> free.
    #pragma unroll
    for (int nt = 0; nt < 7; ++nt) {
        const int t = nt * 16 + l15;
        #pragma unroll
        for (int r = 0; r < 4; ++r)
            slabF[(quad * 4 + r) * 116 + t] = acc2[nt][r];
    }

    // ===== Euler scan (lanes 0..15, lane m = row m): b128 o'-reads, direct global stores =====
    // I_new = I * fma(o', 1-I, 1-dt*gamma); o' pre-scaled by dt.
    if (lane < 16) {
        const f32x4* orow4 = (const f32x4*)(slabF + lane * 116);       // 464 B stride, 16B-aligned
        f32x4* gout = (f32x4*)(out + (size_t)(row0 + lane) * 100);     // this lane's output row
        float prev = I0_C;
        #pragma unroll
        for (int c = 0; c < 25; ++c) {
            const f32x4 o = orow4[c];          // o'[4c .. 4c+3] (o'[99]=0, unused)
            f32x4 v;
            v.x = prev;
            v.y = prev * fmaf(o[0], 1.0f - prev, 1.0f - DT_C * GAMMA_C); prev = v.y;
            v.z = prev * fmaf(o[1], 1.0f - prev, 1.0f - DT_C * GAMMA_C); prev = v.z;
            v.w = prev * fmaf(o[2], 1.0f - prev, 1.0f - DT_C * GAMMA_C); prev = v.w;
            gout[c] = v;
            prev = prev * fmaf(o[3], 1.0f - prev, 1.0f - DT_C * GAMMA_C);
        }
    }
}

extern "C" void kernel_launch(void* const* d_in, const int* in_sizes, int n_in,
                              void* d_out, int out_size, void* d_ws, size_t ws_size,
                              hipStream_t stream) {
    const float* x  = (const float*)d_in[0];
    const float* W0 = (const float*)d_in[1];
    const float* b0 = (const float*)d_in[2];
    const float* W1 = (const float*)d_in[3];
    const float* b1 = (const float*)d_in[4];
    const float* W2 = (const float*)d_in[5];
    const float* b2 = (const float*)d_in[6];
    float* out = (float*)d_out;
    uint16_t* wsu = (uint16_t*)d_ws;

    pack_kernel<<<dim3(80), dim3(256), 0, stream>>>(W0, b0, W1, b1, W2, b2, wsu);
    net_kernel<<<dim3(BB / 64), dim3(256), 0, stream>>>(x, (const void*)wsu, out);
}